// Round 7
// baseline (203.251 us; speedup 1.0000x reference)
//
#include <hip/hip_runtime.h>

// B=2, L=2048, DIM=1024, H=16, HD=64; scale folded into Q: 0.125*log2e; mask: -60*log2e
#define LL 2048
#define NHEADS 16
#define HDIM 64
#define QSCALE 0.18033688011112042f   // 0.125 * log2(e)
#define MASKC1 -86.56170245333780f    // -60 * log2(e)

typedef __attribute__((ext_vector_type(8))) __bf16 bf16x8;
typedef __attribute__((ext_vector_type(4))) float f32x4;
typedef __attribute__((ext_vector_type(4))) unsigned int u32x4;

__device__ __forceinline__ unsigned short f2bf(float f) {
  unsigned int u = __builtin_bit_cast(unsigned int, f);
  u += 0x7fffu + ((u >> 16) & 1u);   // RNE
  return (unsigned short)(u >> 16);
}

__device__ __forceinline__ bf16x8 ld_frag(const unsigned short* p) {
  return *reinterpret_cast<const bf16x8*>(p);
}

__device__ __forceinline__ float bflo(unsigned int u) {
  return __builtin_bit_cast(float, u << 16);
}
__device__ __forceinline__ float bfhi(unsigned int u) {
  return __builtin_bit_cast(float, u & 0xffff0000u);
}
// pack two floats (truncated to bf16) into one u32: low short = lo, high short = hi
__device__ __forceinline__ unsigned int pack2(float hi, float lo) {
  return __builtin_amdgcn_perm(__builtin_bit_cast(unsigned int, hi),
                               __builtin_bit_cast(unsigned int, lo), 0x07060302u);
}

// async global->LDS, 16B per lane; LDS dest = wave-uniform base + lane*16
__device__ __forceinline__ void async_cp16(const unsigned short* g, unsigned short* l) {
  __builtin_amdgcn_global_load_lds(
      (const __attribute__((address_space(1))) unsigned int*)(unsigned long long)(g),
      (__attribute__((address_space(3))) unsigned int*)(unsigned int)(unsigned long long)(l),
      16, 0, 0);
}

// 64B lem prefetch via inline asm (completion guaranteed by counted vmcnt at ITER top)
__device__ __forceinline__ void lem_load(const unsigned short* p, uint4& a, uint4& b,
                                         uint4& c, uint4& d) {
  asm volatile("global_load_dwordx4 %0, %4, off\n\t"
               "global_load_dwordx4 %1, %4, off offset:16\n\t"
               "global_load_dwordx4 %2, %4, off offset:32\n\t"
               "global_load_dwordx4 %3, %4, off offset:48"
               : "=&v"(a), "=&v"(b), "=&v"(c), "=&v"(d)
               : "v"(p)
               : "memory");
}

// ---------------- fused prep: W transpose (z<3) + x fp32->bf16 convert (z==3) ----------------
// grid (16, 16, 4), 256 threads. Saves one kernel launch vs separate cvt_x/transpose_w.
__global__ __launch_bounds__(256) void prep_kernel(const float* __restrict__ x,
                                                   const float* __restrict__ Wq,
                                                   const float* __restrict__ Wk,
                                                   const float* __restrict__ Wv,
                                                   unsigned short* __restrict__ xb,
                                                   unsigned short* __restrict__ WtAll) {
  const int z = blockIdx.z;
  if (z == 3) {
    // x convert: 2*2048*1024 = 4,194,304 floats; 256 blocks x 256 threads x 16 float4
    const int bidx = blockIdx.y * 16 + blockIdx.x;
    const int base = bidx * 256 + threadIdx.x;
#pragma unroll
    for (int p = 0; p < 16; ++p) {
      int i = (p * 65536 + base) * 4;
      float4 v = *reinterpret_cast<const float4*>(x + i);
      ushort4 o;
      o.x = f2bf(v.x); o.y = f2bf(v.y); o.z = f2bf(v.z); o.w = f2bf(v.w);
      *reinterpret_cast<ushort4*>(xb + i) = o;
    }
    return;
  }
  const float* W = (z == 0) ? Wq : (z == 1) ? Wk : Wv;
  unsigned short* dst = WtAll + (size_t)z * 1024 * 1024;
  int n0 = blockIdx.x * 64, k0 = blockIdx.y * 64;
  __shared__ float t[64][65];
  int tx = threadIdx.x & 63, ty = threadIdx.x >> 6;
#pragma unroll
  for (int p = 0; p < 16; ++p) {
    int kr = p * 4 + ty;
    t[kr][tx] = W[(size_t)(k0 + kr) * 1024 + n0 + tx];
  }
  __syncthreads();
#pragma unroll
  for (int p = 0; p < 16; ++p) {
    int nr = p * 4 + ty;
    dst[(size_t)(n0 + nr) * 1024 + k0 + tx] = f2bf(t[tx][nr]);
  }
}

// ---------------- prep: lem = bf16(mask*MASKC1), per-flash-thread packed ----------------
// Output layout [b][qb(16)][kt(32)][tid(256)][32 shorts = 64B]; 32 shorts ordered
// idx = mt*16 + nt*4 + r  for value lem[q = qb*128 + w*32 + mt*16 + cc][k = kt*64 + nt*16 + g*4 + r].
__global__ __launch_bounds__(256) void lem_prep_kernel(const float* __restrict__ mask,
                                                       unsigned short* __restrict__ lem) {
  const int qb = blockIdx.x, kt = blockIdx.y, b = blockIdx.z;
  const int tid = threadIdx.x;
  __shared__ unsigned short lds[128 * 72];
  {
    const int r0 = tid >> 4;          // 0..15
    const int c0 = (tid & 15) * 4;    // 0..60
#pragma unroll
    for (int p = 0; p < 8; ++p) {
      int row = p * 16 + r0;
      float4 v = *reinterpret_cast<const float4*>(
          mask + ((size_t)b * LL + qb * 128 + row) * LL + kt * 64 + c0);
      ushort4 o;
      o.x = f2bf(v.x * MASKC1); o.y = f2bf(v.y * MASKC1);
      o.z = f2bf(v.z * MASKC1); o.w = f2bf(v.w * MASKC1);
      *reinterpret_cast<ushort4*>(&lds[row * 72 + c0]) = o;
    }
  }
  __syncthreads();
  const int w = tid >> 6, lane = tid & 63, g = lane >> 4, cc = lane & 15;
  unsigned int ow[16];
#pragma unroll
  for (int mt = 0; mt < 2; ++mt) {
    const int q = w * 32 + mt * 16 + cc;
#pragma unroll
    for (int nt = 0; nt < 4; ++nt) {
      uint2 v = *reinterpret_cast<const uint2*>(&lds[q * 72 + nt * 16 + g * 4]);
      ow[mt * 8 + nt * 2]     = v.x;   // r0 (lo), r1 (hi)
      ow[mt * 8 + nt * 2 + 1] = v.y;   // r2 (lo), r3 (hi)
    }
  }
  uint4* dst = reinterpret_cast<uint4*>(
      lem + ((((size_t)b * 16 + qb) * 32 + kt) * 256 + tid) * 32);
#pragma unroll
  for (int j = 0; j < 4; ++j)
    dst[j] = make_uint4(ow[4 * j], ow[4 * j + 1], ow[4 * j + 2], ow[4 * j + 3]);
}

// ---------------- QKV projection GEMM (m97-style async staging, swizzled rows) ----------------
// [reverted to the proven round-5 structure: 49.5 µs; the BK=32 counted-vmcnt port
//  regressed to 58 µs — qkv's stall is not the barrier drain]
// grid (8, 32, 3). z==0: Q bf16 [bh][l][d] * QSCALE; z==1: K; z==2: V^T [bh][d][pos], key-permuted
// with pos(key6) = (key6>>5)*32 + ((key6>>2)&3)*8 + ((key6>>4)&1)*4 + (key6&3).
__global__ __launch_bounds__(256) void qkv_gemm_kernel(
    const unsigned short* __restrict__ xb, const unsigned short* __restrict__ WtAll,
    const float* __restrict__ bq, const float* __restrict__ bk, const float* __restrict__ bv,
    unsigned short* __restrict__ qkv) {
  const int z = blockIdx.z;
  const unsigned short* Wt = WtAll + (size_t)z * 1024 * 1024;
  const float* bias = (z == 0) ? bq : (z == 1) ? bk : bv;
  unsigned short* outb = qkv + (size_t)z * 4194304;

  __shared__ __align__(16) unsigned short smem[16384];  // As 8192, Bs 8192 (stride 64, swizzled)
  unsigned short* As = smem;
  unsigned short* Bs = smem + 8192;

  const int tid = threadIdx.x;
  const int w = tid >> 6, lane = tid & 63, g = lane >> 4, cc = lane & 15;
  const int wm = w >> 1, wn = w & 1;
  const int m0 = blockIdx.y * 128, n0 = blockIdx.x * 128;
  const int srow = lane >> 3;                 // row within seg
  const int gc = ((lane & 7) - srow) & 7;     // swizzle: LDS slot s holds chunk (s - row)&7
  const unsigned short* ga = xb + (size_t)(m0 + w * 32 + srow) * 1024 + gc * 8;
  const unsigned short* gb = Wt + (size_t)(n0 + w * 32 + srow) * 1024 + gc * 8;
  unsigned short* la = As + w * 2048;   // 4 segs * 512
  unsigned short* lb = Bs + w * 2048;

  f32x4 acc[4][4];
#pragma unroll
  for (int i = 0; i < 4; ++i)
#pragma unroll
    for (int j = 0; j < 4; ++j) acc[i][j] = (f32x4)0.0f;

  for (int kk = 0; kk < 1024; kk += 64) {
    __syncthreads();
#pragma unroll
    for (int i = 0; i < 4; ++i) {
      async_cp16(ga + i * 8192 + kk, la + i * 512);
      async_cp16(gb + i * 8192 + kk, lb + i * 512);
    }
    __syncthreads();  // compiler emits vmcnt(0) drain before barrier
    bf16x8 af[4][2], bfr[4][2];
#pragma unroll
    for (int mt = 0; mt < 4; ++mt)
#pragma unroll
      for (int ks = 0; ks < 2; ++ks)
        af[mt][ks] = ld_frag(&As[(wm * 64 + mt * 16 + cc) * 64 + ((4 * ks + g + cc) & 7) * 8]);
#pragma unroll
    for (int nt = 0; nt < 4; ++nt)
#pragma unroll
      for (int ks = 0; ks < 2; ++ks)
        bfr[nt][ks] = ld_frag(&Bs[(wn * 64 + nt * 16 + cc) * 64 + ((4 * ks + g + cc) & 7) * 8]);
#pragma unroll
    for (int mt = 0; mt < 4; ++mt)
#pragma unroll
      for (int nt = 0; nt < 4; ++nt)
#pragma unroll
        for (int ks = 0; ks < 2; ++ks)
          acc[mt][nt] = __builtin_amdgcn_mfma_f32_16x16x32_bf16(af[mt][ks], bfr[nt][ks],
                                                                acc[mt][nt], 0, 0, 0);
  }

  if (z != 2) {
    const float sc = (z == 0) ? QSCALE : 1.0f;
#pragma unroll
    for (int nt = 0; nt < 4; ++nt) {
      int n = n0 + wn * 64 + nt * 16 + cc;
      float bval = bias[n];
      int h = n >> 6, d = n & 63;
#pragma unroll
      for (int mt = 0; mt < 4; ++mt) {
#pragma unroll
        for (int r = 0; r < 4; ++r) {
          int m = m0 + wm * 64 + mt * 16 + g * 4 + r;
          int b = m >> 11, l = m & 2047;
          outb[(((size_t)(b * NHEADS + h) * LL) + l) * HDIM + d] =
              f2bf((acc[mt][nt][r] + bval) * sc);
        }
      }
    }
  } else {
    // V^T epilogue with key permutation: key6 = mt*16 + g*4 + r
    // -> pos = (mt>>1)*32 + g*8 + (mt&1)*4 + r   (inverse of flash's in-register P layout)
    __syncthreads();
#pragma unroll
    for (int nt = 0; nt < 4; ++nt) {
      int nr = wn * 64 + nt * 16 + cc;
      float bval = bias[n0 + nr];
#pragma unroll
      for (int mt = 0; mt < 4; ++mt)
#pragma unroll
        for (int r = 0; r < 4; ++r)
          smem[nr * 128 + wm * 64 + (mt >> 1) * 32 + g * 8 + (mt & 1) * 4 + r] =
              f2bf(acc[mt][nt][r] + bval);
    }
    __syncthreads();
    int row = tid >> 1, half = tid & 1;
    int n = n0 + row, hh = n >> 6, dd = n & 63;
    int bb = m0 >> 11, l0 = (m0 & 2047) + half * 64;
    unsigned short* dst = outb + ((size_t)(bb * NHEADS + hh) * HDIM + dd) * LL + l0;
#pragma unroll
    for (int i = 0; i < 8; ++i)
      *reinterpret_cast<uint4*>(dst + i * 8) =
          *reinterpret_cast<const uint4*>(&smem[row * 128 + half * 64 + i * 8]);
  }
}

// ---------------- flash attention ----------------
// grid (16, 32): q-tile 128, 4 waves x 32 q-rows, 2 blocks/CU. Swapped QK^T; P packed
// in-register into PV A-frags (key-permuted V^T); lem folded into MFMA C-init.
// T3/T4 schedule: 3 LDS buffers, stage(kt+2) each iter (4 cp16 + 4 asm lem = 8 VMEM),
// raw s_barrier with COUNTED s_waitcnt vmcnt(8). li via ones-MFMA.
__global__ __launch_bounds__(256, 2) void flash_kernel(
    const unsigned short* __restrict__ Qb, const unsigned short* __restrict__ Kb,
    const unsigned short* __restrict__ Vt, const unsigned short* __restrict__ Lem,
    float* __restrict__ out) {
  const int id = blockIdx.y * 16 + blockIdx.x;   // 512 blocks
  const int nid = (id & 7) * 64 + (id >> 3);     // bijective XCD swizzle (512 % 8 == 0)
  const int qb = nid & 15, bh = nid >> 4;
  const int b = bh >> 4, h = bh & 15;
  const int q0 = qb * 128;
  const int tid = threadIdx.x, w = tid >> 6, lane = tid & 63, g = lane >> 4, cc = lane & 15;
  const size_t bhoff = (size_t)bh * LL * HDIM;

  __shared__ __align__(16) unsigned short Ks[3][64 * 64];  // [key][d], swizzled chunks
  __shared__ __align__(16) unsigned short Vs[3][64 * 64];  // [d][pos], swizzled chunks

  bf16x8 aq[2][2];
#pragma unroll
  for (int mt = 0; mt < 2; ++mt)
#pragma unroll
    for (int ks = 0; ks < 2; ++ks)
      aq[mt][ks] = *reinterpret_cast<const bf16x8*>(
          Qb + bhoff + (size_t)(q0 + w * 32 + mt * 16 + cc) * HDIM + ks * 32 + g * 8);

  const int srow = lane >> 3;
  const int gcs = ((lane & 7) - srow) & 7;
  const unsigned short* kg0 = Kb + bhoff + (size_t)(w * 8 + srow) * HDIM + gcs * 8;
  const unsigned short* kg1 = Kb + bhoff + (size_t)(32 + w * 8 + srow) * HDIM + gcs * 8;
  const unsigned short* vg0 = Vt + bhoff + (size_t)(w * 8 + srow) * LL + gcs * 8;
  const unsigned short* vg1 = Vt + bhoff + (size_t)(32 + w * 8 + srow) * LL + gcs * 8;

  const unsigned short* lemq = Lem + (((size_t)b * 16 + qb) * 32 * 256 + tid) * 32;

  const u32x4 onesu = {0x3F803F80u, 0x3F803F80u, 0x3F803F80u, 0x3F803F80u};
  const bf16x8 bones = __builtin_bit_cast(bf16x8, onesu);

  uint4 l00, l01, l02, l03, l10, l11, l12, l13, l20, l21, l22, l23;

  f32x4 liacc[2];
  f32x4 oacc[2][4];
#pragma unroll
  for (int mt = 0; mt < 2; ++mt) {
    liacc[mt] = (f32x4)0.0f;
#pragma unroll
    for (int nt = 0; nt < 4; ++nt) oacc[mt][nt] = (f32x4)0.0f;
  }

  async_cp16(kg0, Ks[0] + w * 512);
  async_cp16(kg1, Ks[0] + (w + 4) * 512);
  async_cp16(vg0, Vs[0] + w * 512);
  async_cp16(vg1, Vs[0] + (w + 4) * 512);
  lem_load(lemq, l00, l01, l02, l03);
  lemq += 8192;
  async_cp16(kg0 + (size_t)64 * HDIM, Ks[1] + w * 512);
  async_cp16(kg1 + (size_t)64 * HDIM, Ks[1] + (w + 4) * 512);
  async_cp16(vg0 + 64, Vs[1] + w * 512);
  async_cp16(vg1 + 64, Vs[1] + (w + 4) * 512);
  lem_load(lemq, l10, l11, l12, l13);
  lemq += 8192;

#define FLASH_COMPUTE(BUF, LSA, LSB, LSC, LSD)                                         \
  {                                                                                    \
    bf16x8 bk_[4][2], bv[4][2];                                                        \
    _Pragma("unroll") for (int nt = 0; nt < 4; ++nt)                                   \
      _Pragma("unroll") for (int ks = 0; ks < 2; ++ks)                                 \
        bk_[nt][ks] =                                                                  \
            ld_frag(&Ks[BUF][(nt * 16 + cc) * 64 + ((4 * ks + g + cc) & 7) * 8]);      \
    _Pragma("unroll") for (int nt = 0; nt < 4; ++nt)                                   \
      _Pragma("unroll") for (int ks = 0; ks < 2; ++ks)                                 \
        bv[nt][ks] =                                                                   \
            ld_frag(&Vs[BUF][(nt * 16 + cc) * 64 + ((4 * ks + g + cc) & 7) * 8]);      \
    bf16x8 ap[2][2];                                                                   \
    _Pragma("unroll") for (int mt = 0; mt < 2; ++mt) {                                 \
      f32x4 sacc[4];                                                                   \
      const uint4 ea = (mt == 0) ? LSA : LSC;                                          \
      const uint4 eb = (mt == 0) ? LSB : LSD;                                          \
      sacc[0][0] = bflo(ea.x); sacc[0][1] = bfhi(ea.x);                                \
      sacc[0][2] = bflo(ea.y); sacc[0][3] = bfhi(ea.y);                                \
      sacc[1][0] = bflo(ea.z); sacc[1][1] = bfhi(ea.z);                                \
      sacc[1][2] = bflo(ea.w); sacc[1][3] = bfhi(ea.w);                                \
      sacc[2][0] = bflo(eb.x); sacc[2][1] = bfhi(eb.x);                                \
      sacc[2][2] = bflo(eb.y); sacc[2][3] = bfhi(eb.y);                                \
      sacc[3][0] = bflo(eb.z); sacc[3][1] = bfhi(eb.z);                                \
      sacc[3][2] = bflo(eb.w); sacc[3][3] = bfhi(eb.w);                                \
      _Pragma("unroll") for (int nt = 0; nt < 4; ++nt)                                 \
        _Pragma("unroll") for (int ks = 0; ks < 2; ++ks)                               \
          sacc[nt] = __builtin_amdgcn_mfma_f32_16x16x32_bf16(bk_[nt][ks], aq[mt][ks],  \
                                                             sacc[nt], 0, 0, 0);       \
      float p[4][4];                                                                   \
      _Pragma("unroll") for (int nt = 0; nt < 4; ++nt)                                 \
        _Pragma("unroll") for (int r = 0; r < 4; ++r)                                  \
          p[nt][r] = __builtin_amdgcn_exp2f(sacc[nt][r]);                              \
      unsigned int wd[8];                                                              \
      _Pragma("unroll") for (int ks = 0; ks < 2; ++ks) {                               \
        wd[ks * 4 + 0] = pack2(p[2 * ks][1],     p[2 * ks][0]);                        \
        wd[ks * 4 + 1] = pack2(p[2 * ks][3],     p[2 * ks][2]);                        \
        wd[ks * 4 + 2] = pack2(p[2 * ks + 1][1], p[2 * ks + 1][0]);                    \
        wd[ks * 4 + 3] = pack2(p[2 * ks + 1][3], p[2 * ks + 1][2]);                    \
        u32x4 uv = {wd[ks * 4], wd[ks * 4 + 1], wd[ks * 4 + 2], wd[ks * 4 + 3]};       \
        ap[mt][ks] = __builtin_bit_cast(bf16x8, uv);                                   \
      }                                                                                \
    }                                                                                  \
    _Pragma("unroll") for (int mt = 0; mt < 2; ++mt) {                                 \
      _Pragma("unroll") for (int nt = 0; nt < 4; ++nt)                                 \
        _Pragma("unroll") for (int ks = 0; ks < 2; ++ks)                               \
          oacc[mt][nt] = __builtin_amdgcn_mfma_f32_16x16x32_bf16(ap[mt][ks], bv[nt][ks],\
                                                                 oacc[mt][nt], 0, 0, 0);\
      _Pragma("unroll") for (int ks = 0; ks < 2; ++ks)                                 \
        liacc[mt] = __builtin_amdgcn_mfma_f32_16x16x32_bf16(ap[mt][ks], bones,         \
                                                            liacc[mt], 0, 0, 0);       \
    }                                                                                  \
  }

#define FITER(KT, CBUF, SBUF, VMC, ISSUE, UA, UB, UC, UD, LA, LB, LC, LD)              \
  {                                                                                    \
    asm volatile("s_waitcnt vmcnt(" VMC ")" ::: "memory");                             \
    __builtin_amdgcn_sched_barrier(0);                                                 \
    asm volatile("s_barrier" ::: "memory");                                            \
    __builtin_amdgcn_sched_barrier(0);                                                 \
    if (ISSUE) {                                                                       \
      const size_t ko = (size_t)((KT) + 2) * 64;                                       \
      async_cp16(kg0 + ko * HDIM, Ks[SBUF] + w * 512);                                 \
      async_cp16(kg1 + ko * HDIM, Ks[SBUF] + (w + 4) * 512);                           \
      async_cp16(vg0 + ko, Vs[SBUF] + w * 512);                                        \
      async_cp16(vg1 + ko, Vs[SBUF] + (w + 4) * 512);                                  \
      lem_load(lemq, LA, LB, LC, LD);                                                  \
      lemq += 8192;                                                                    \
    }                                                                                  \
    FLASH_COMPUTE(CBUF, UA, UB, UC, UD);                                               \
  }

  for (int kt = 0; kt < 30; kt += 3) {
    FITER(kt + 0, 0, 2, "8", true,  l00, l01, l02, l03, l20, l21, l22, l23)
    FITER(kt + 1, 1, 0, "8", true,  l10, l11, l12, l13, l00, l01, l02, l03)
    FITER(kt + 2, 2, 1, "8", true,  l20, l21, l22, l23, l10, l11, l12, l13)
  }
  FITER(30, 0, 0, "8", false, l00, l01, l02, l03, l00, l01, l02, l03)
  FITER(31, 1, 0, "0", false, l10, l11, l12, l13, l10, l11, l12, l13)

#undef FITER
#undef FLASH_COMPUTE

#pragma unroll
  for (int mt = 0; mt < 2; ++mt) {
#pragma unroll
    for (int r = 0; r < 4; ++r) {
      float inv = 1.0f / liacc[mt][r];
      int qrow = q0 + w * 32 + mt * 16 + g * 4 + r;
#pragma unroll
      for (int nt = 0; nt < 4; ++nt)
        out[((size_t)b * LL + qrow) * 1024 + h * 64 + nt * 16 + cc] = oacc[mt][nt][r] * inv;
    }
  }
}

extern "C" void kernel_launch(void* const* d_in, const int* in_sizes, int n_in,
                              void* d_out, int out_size, void* d_ws, size_t ws_size,
                              hipStream_t stream) {
  const float* x    = (const float*)d_in[0];
  const float* mask = (const float*)d_in[1];
  const float* Wq   = (const float*)d_in[2];
  const float* bq   = (const float*)d_in[3];
  const float* Wk   = (const float*)d_in[4];
  const float* bk   = (const float*)d_in[5];
  const float* Wv   = (const float*)d_in[6];
  const float* bv   = (const float*)d_in[7];
  float* out = (float*)d_out;
  (void)in_sizes; (void)n_in; (void)out_size; (void)ws_size;

  char* ws = (char*)d_ws;
  // layout: qkv @0 (24 MiB); xb @24 (8 MiB); Wt @32 (6 MiB);
  // lem @24 (16 MiB) overlaps xb/Wt — dead after qkv_gemm (same-stream serialization)
  unsigned short* qkv = (unsigned short*)(ws);
  unsigned short* xb  = (unsigned short*)(ws + (24u << 20));
  unsigned short* Wt  = (unsigned short*)(ws + (32u << 20));
  unsigned short* lem = (unsigned short*)(ws + (24u << 20));

  prep_kernel<<<dim3(16, 16, 4), dim3(256), 0, stream>>>(x, Wq, Wk, Wv, xb, Wt);
  qkv_gemm_kernel<<<dim3(8, 32, 3), dim3(256), 0, stream>>>(xb, Wt, bq, bk, bv, qkv);
  lem_prep_kernel<<<dim3(16, 32, 2), dim3(256), 0, stream>>>(mask, lem);
  flash_kernel<<<dim3(16, 32), dim3(256), 0, stream>>>(qkv, qkv + 4194304, qkv + 8388608,
                                                       lem, out);
}

// Round 8
// 188.411 us; speedup vs baseline: 1.0788x; 1.0788x over previous
//
#include <hip/hip_runtime.h>

// B=2, L=2048, DIM=1024, H=16, HD=64; scale folded into Q: 0.125*log2e; mask: -60*log2e
#define LL 2048
#define NHEADS 16
#define HDIM 64
#define QSCALE 0.18033688011112042f   // 0.125 * log2(e)
#define MASKC1 -86.56170245333780f    // -60 * log2(e)

typedef __attribute__((ext_vector_type(8))) __bf16 bf16x8;
typedef __attribute__((ext_vector_type(4))) float f32x4;
typedef __attribute__((ext_vector_type(4))) unsigned int u32x4;

__device__ __forceinline__ unsigned short f2bf(float f) {
  unsigned int u = __builtin_bit_cast(unsigned int, f);
  u += 0x7fffu + ((u >> 16) & 1u);   // RNE
  return (unsigned short)(u >> 16);
}

__device__ __forceinline__ bf16x8 ld_frag(const unsigned short* p) {
  return *reinterpret_cast<const bf16x8*>(p);
}

__device__ __forceinline__ float bflo(unsigned int u) {
  return __builtin_bit_cast(float, u << 16);
}
__device__ __forceinline__ float bfhi(unsigned int u) {
  return __builtin_bit_cast(float, u & 0xffff0000u);
}
// pack two floats (truncated to bf16) into one u32: low short = lo, high short = hi
__device__ __forceinline__ unsigned int pack2(float hi, float lo) {
  return __builtin_amdgcn_perm(__builtin_bit_cast(unsigned int, hi),
                               __builtin_bit_cast(unsigned int, lo), 0x07060302u);
}

// async global->LDS, 16B per lane; LDS dest = wave-uniform base + lane*16
__device__ __forceinline__ void async_cp16(const unsigned short* g, unsigned short* l) {
  __builtin_amdgcn_global_load_lds(
      (const __attribute__((address_space(1))) unsigned int*)(unsigned long long)(g),
      (__attribute__((address_space(3))) unsigned int*)(unsigned int)(unsigned long long)(l),
      16, 0, 0);
}

// 64B lem prefetch via inline asm (completion guaranteed by counted vmcnt at ITER top)
__device__ __forceinline__ void lem_load(const unsigned short* p, uint4& a, uint4& b,
                                         uint4& c, uint4& d) {
  asm volatile("global_load_dwordx4 %0, %4, off\n\t"
               "global_load_dwordx4 %1, %4, off offset:16\n\t"
               "global_load_dwordx4 %2, %4, off offset:32\n\t"
               "global_load_dwordx4 %3, %4, off offset:48"
               : "=&v"(a), "=&v"(b), "=&v"(c), "=&v"(d)
               : "v"(p)
               : "memory");
}

// ---------------- fused prep: W transpose (z<3) + x fp32->bf16 convert (z==3) ----------------
__global__ __launch_bounds__(256) void prep_kernel(const float* __restrict__ x,
                                                   const float* __restrict__ Wq,
                                                   const float* __restrict__ Wk,
                                                   const float* __restrict__ Wv,
                                                   unsigned short* __restrict__ xb,
                                                   unsigned short* __restrict__ WtAll) {
  const int z = blockIdx.z;
  if (z == 3) {
    const int bidx = blockIdx.y * 16 + blockIdx.x;
    const int base = bidx * 256 + threadIdx.x;
#pragma unroll
    for (int p = 0; p < 16; ++p) {
      int i = (p * 65536 + base) * 4;
      float4 v = *reinterpret_cast<const float4*>(x + i);
      ushort4 o;
      o.x = f2bf(v.x); o.y = f2bf(v.y); o.z = f2bf(v.z); o.w = f2bf(v.w);
      *reinterpret_cast<ushort4*>(xb + i) = o;
    }
    return;
  }
  const float* W = (z == 0) ? Wq : (z == 1) ? Wk : Wv;
  unsigned short* dst = WtAll + (size_t)z * 1024 * 1024;
  int n0 = blockIdx.x * 64, k0 = blockIdx.y * 64;
  __shared__ float t[64][65];
  int tx = threadIdx.x & 63, ty = threadIdx.x >> 6;
#pragma unroll
  for (int p = 0; p < 16; ++p) {
    int kr = p * 4 + ty;
    t[kr][tx] = W[(size_t)(k0 + kr) * 1024 + n0 + tx];
  }
  __syncthreads();
#pragma unroll
  for (int p = 0; p < 16; ++p) {
    int nr = p * 4 + ty;
    dst[(size_t)(n0 + nr) * 1024 + k0 + tx] = f2bf(t[tx][nr]);
  }
}

// ---------------- prep: lem = bf16(mask*MASKC1), per-flash-thread packed ----------------
// Output layout [b][qb(16)][kt(32)][tid(256)][32 shorts = 64B]; 32 shorts ordered
// idx = mt*16 + nt*4 + r  for value lem[q = qb*128 + w*32 + mt*16 + cc][k = kt*64 + nt*16 + g*4 + r].
__global__ __launch_bounds__(256) void lem_prep_kernel(const float* __restrict__ mask,
                                                       unsigned short* __restrict__ lem) {
  const int qb = blockIdx.x, kt = blockIdx.y, b = blockIdx.z;
  const int tid = threadIdx.x;
  __shared__ unsigned short lds[128 * 72];
  {
    const int r0 = tid >> 4;          // 0..15
    const int c0 = (tid & 15) * 4;    // 0..60
#pragma unroll
    for (int p = 0; p < 8; ++p) {
      int row = p * 16 + r0;
      float4 v = *reinterpret_cast<const float4*>(
          mask + ((size_t)b * LL + qb * 128 + row) * LL + kt * 64 + c0);
      ushort4 o;
      o.x = f2bf(v.x * MASKC1); o.y = f2bf(v.y * MASKC1);
      o.z = f2bf(v.z * MASKC1); o.w = f2bf(v.w * MASKC1);
      *reinterpret_cast<ushort4*>(&lds[row * 72 + c0]) = o;
    }
  }
  __syncthreads();
  const int w = tid >> 6, lane = tid & 63, g = lane >> 4, cc = lane & 15;
  unsigned int ow[16];
#pragma unroll
  for (int mt = 0; mt < 2; ++mt) {
    const int q = w * 32 + mt * 16 + cc;
#pragma unroll
    for (int nt = 0; nt < 4; ++nt) {
      uint2 v = *reinterpret_cast<const uint2*>(&lds[q * 72 + nt * 16 + g * 4]);
      ow[mt * 8 + nt * 2]     = v.x;   // r0 (lo), r1 (hi)
      ow[mt * 8 + nt * 2 + 1] = v.y;   // r2 (lo), r3 (hi)
    }
  }
  uint4* dst = reinterpret_cast<uint4*>(
      lem + ((((size_t)b * 16 + qb) * 32 + kt) * 256 + tid) * 32);
#pragma unroll
  for (int j = 0; j < 4; ++j)
    dst[j] = make_uint4(ow[4 * j], ow[4 * j + 1], ow[4 * j + 2], ow[4 * j + 3]);
}

// ---------------- QKV projection GEMM (BK=64 double-buffer, counted vmcnt) ----------------
// grid (8, 32, 3). Same proven compute body / LDS layout / swizzle as the 50µs version;
// ONLY the sync structure changed: raw s_barrier + s_waitcnt vmcnt(8) (counted, never 0
// in steady state), stage(kt+2) issued after a second bare barrier into the buffer just
// consumed. Tile kt+1 stays in flight across the barrier -> per-iter HBM latency hidden.
// No sched_barrier pins: ds_read/MFMA ordering via data deps + asm memory clobbers.
__global__ __launch_bounds__(256) void qkv_gemm_kernel(
    const unsigned short* __restrict__ xb, const unsigned short* __restrict__ WtAll,
    const float* __restrict__ bq, const float* __restrict__ bk, const float* __restrict__ bv,
    unsigned short* __restrict__ qkv) {
  const int z = blockIdx.z;
  const unsigned short* Wt = WtAll + (size_t)z * 1024 * 1024;
  const float* bias = (z == 0) ? bq : (z == 1) ? bk : bv;
  unsigned short* outb = qkv + (size_t)z * 4194304;

  // buf0: As@0, Bs@8192; buf1: As@16384, Bs@24576 (shorts). 64 KB -> 2 blocks/CU.
  __shared__ __align__(16) unsigned short smem[32768];

  const int tid = threadIdx.x;
  const int w = tid >> 6, lane = tid & 63, g = lane >> 4, cc = lane & 15;
  const int wm = w >> 1, wn = w & 1;
  const int m0 = blockIdx.y * 128, n0 = blockIdx.x * 128;
  const int srow = lane >> 3;                 // row within seg
  const int gc = ((lane & 7) - srow) & 7;     // swizzle: LDS slot s holds chunk (s - row)&7
  const unsigned short* ga = xb + (size_t)(m0 + w * 32 + srow) * 1024 + gc * 8;
  const unsigned short* gb = Wt + (size_t)(n0 + w * 32 + srow) * 1024 + gc * 8;

  f32x4 acc[4][4];
#pragma unroll
  for (int i = 0; i < 4; ++i)
#pragma unroll
    for (int j = 0; j < 4; ++j) acc[i][j] = (f32x4)0.0f;

  // prologue: stage tile 0 -> buf0, tile 1 -> buf1 (8 VMEM ops each)
#pragma unroll
  for (int i = 0; i < 4; ++i) {
    async_cp16(ga + i * 8192, smem + w * 2048 + i * 512);
    async_cp16(gb + i * 8192, smem + 8192 + w * 2048 + i * 512);
  }
#pragma unroll
  for (int i = 0; i < 4; ++i) {
    async_cp16(ga + i * 8192 + 64, smem + 16384 + w * 2048 + i * 512);
    async_cp16(gb + i * 8192 + 64, smem + 24576 + w * 2048 + i * 512);
  }

#define QITER(KT, BUF, VMC, ISSUE)                                                     \
  {                                                                                    \
    asm volatile("s_waitcnt vmcnt(" VMC ")" ::: "memory");                             \
    asm volatile("s_barrier" ::: "memory");                                            \
    {                                                                                  \
      const unsigned short* Ab = smem + (BUF) * 16384;                                 \
      const unsigned short* Bb = smem + (BUF) * 16384 + 8192;                          \
      bf16x8 af[4][2], bfr[4][2];                                                      \
      _Pragma("unroll") for (int mt = 0; mt < 4; ++mt)                                 \
        _Pragma("unroll") for (int ks = 0; ks < 2; ++ks)                               \
          af[mt][ks] =                                                                 \
              ld_frag(&Ab[(wm * 64 + mt * 16 + cc) * 64 + ((4 * ks + g + cc) & 7) * 8]);\
      _Pragma("unroll") for (int nt = 0; nt < 4; ++nt)                                 \
        _Pragma("unroll") for (int ks = 0; ks < 2; ++ks)                               \
          bfr[nt][ks] =                                                                \
              ld_frag(&Bb[(wn * 64 + nt * 16 + cc) * 64 + ((4 * ks + g + cc) & 7) * 8]);\
      _Pragma("unroll") for (int mt = 0; mt < 4; ++mt)                                 \
        _Pragma("unroll") for (int nt = 0; nt < 4; ++nt)                               \
          _Pragma("unroll") for (int ks = 0; ks < 2; ++ks)                             \
            acc[mt][nt] = __builtin_amdgcn_mfma_f32_16x16x32_bf16(af[mt][ks], bfr[nt][ks],\
                                                                  acc[mt][nt], 0, 0, 0);\
    }                                                                                  \
    asm volatile("s_barrier" ::: "memory");                                            \
    if (ISSUE) {                                                                       \
      _Pragma("unroll") for (int i = 0; i < 4; ++i) {                                  \
        async_cp16(ga + i * 8192 + ((KT) + 2) * 64, smem + (BUF) * 16384 + w * 2048 + i * 512);\
        async_cp16(gb + i * 8192 + ((KT) + 2) * 64,                                    \
                   smem + (BUF) * 16384 + 8192 + w * 2048 + i * 512);                  \
      }                                                                                \
    }                                                                                  \
  }

  // iters 0..13 issue tile kt+2; 14 and 15 drain
  for (int kt = 0; kt < 14; kt += 2) {
    QITER(kt + 0, 0, "8", true)
    QITER(kt + 1, 1, "8", true)
  }
  QITER(14, 0, "8", false)
  QITER(15, 1, "0", false)

#undef QITER

  if (z != 2) {
    const float sc = (z == 0) ? QSCALE : 1.0f;
#pragma unroll
    for (int nt = 0; nt < 4; ++nt) {
      int n = n0 + wn * 64 + nt * 16 + cc;
      float bval = bias[n];
      int h = n >> 6, d = n & 63;
#pragma unroll
      for (int mt = 0; mt < 4; ++mt) {
#pragma unroll
        for (int r = 0; r < 4; ++r) {
          int m = m0 + wm * 64 + mt * 16 + g * 4 + r;
          int b = m >> 11, l = m & 2047;
          outb[(((size_t)(b * NHEADS + h) * LL) + l) * HDIM + d] =
              f2bf((acc[mt][nt][r] + bval) * sc);
        }
      }
    }
  } else {
    // V^T epilogue with key permutation: key6 = mt*16 + g*4 + r
    // -> pos = (mt>>1)*32 + g*8 + (mt&1)*4 + r   (inverse of flash's in-register P layout)
    __syncthreads();
#pragma unroll
    for (int nt = 0; nt < 4; ++nt) {
      int nr = wn * 64 + nt * 16 + cc;
      float bval = bias[n0 + nr];
#pragma unroll
      for (int mt = 0; mt < 4; ++mt)
#pragma unroll
        for (int r = 0; r < 4; ++r)
          smem[nr * 128 + wm * 64 + (mt >> 1) * 32 + g * 8 + (mt & 1) * 4 + r] =
              f2bf(acc[mt][nt][r] + bval);
    }
    __syncthreads();
    int row = tid >> 1, half = tid & 1;
    int n = n0 + row, hh = n >> 6, dd = n & 63;
    int bb = m0 >> 11, l0 = (m0 & 2047) + half * 64;
    unsigned short* dst = outb + ((size_t)(bb * NHEADS + hh) * HDIM + dd) * LL + l0;
#pragma unroll
    for (int i = 0; i < 8; ++i)
      *reinterpret_cast<uint4*>(dst + i * 8) =
          *reinterpret_cast<const uint4*>(&smem[row * 128 + half * 64 + i * 8]);
  }
}

// ---------------- flash attention ----------------
// grid (16, 32): q-tile 128, 4 waves x 32 q-rows, 2 blocks/CU. Swapped QK^T; P packed
// in-register into PV A-frags (key-permuted V^T); lem folded into MFMA C-init.
// T3/T4 schedule: 3 LDS buffers, stage(kt+2) each iter (4 cp16 + 4 asm lem = 8 VMEM),
// raw s_barrier with COUNTED s_waitcnt vmcnt(8). li via ones-MFMA.
__global__ __launch_bounds__(256, 2) void flash_kernel(
    const unsigned short* __restrict__ Qb, const unsigned short* __restrict__ Kb,
    const unsigned short* __restrict__ Vt, const unsigned short* __restrict__ Lem,
    float* __restrict__ out) {
  const int id = blockIdx.y * 16 + blockIdx.x;   // 512 blocks
  const int nid = (id & 7) * 64 + (id >> 3);     // bijective XCD swizzle (512 % 8 == 0)
  const int qb = nid & 15, bh = nid >> 4;
  const int b = bh >> 4, h = bh & 15;
  const int q0 = qb * 128;
  const int tid = threadIdx.x, w = tid >> 6, lane = tid & 63, g = lane >> 4, cc = lane & 15;
  const size_t bhoff = (size_t)bh * LL * HDIM;

  __shared__ __align__(16) unsigned short Ks[3][64 * 64];  // [key][d], swizzled chunks
  __shared__ __align__(16) unsigned short Vs[3][64 * 64];  // [d][pos], swizzled chunks

  bf16x8 aq[2][2];
#pragma unroll
  for (int mt = 0; mt < 2; ++mt)
#pragma unroll
    for (int ks = 0; ks < 2; ++ks)
      aq[mt][ks] = *reinterpret_cast<const bf16x8*>(
          Qb + bhoff + (size_t)(q0 + w * 32 + mt * 16 + cc) * HDIM + ks * 32 + g * 8);

  const int srow = lane >> 3;
  const int gcs = ((lane & 7) - srow) & 7;
  const unsigned short* kg0 = Kb + bhoff + (size_t)(w * 8 + srow) * HDIM + gcs * 8;
  const unsigned short* kg1 = Kb + bhoff + (size_t)(32 + w * 8 + srow) * HDIM + gcs * 8;
  const unsigned short* vg0 = Vt + bhoff + (size_t)(w * 8 + srow) * LL + gcs * 8;
  const unsigned short* vg1 = Vt + bhoff + (size_t)(32 + w * 8 + srow) * LL + gcs * 8;

  const unsigned short* lemq = Lem + (((size_t)b * 16 + qb) * 32 * 256 + tid) * 32;

  const u32x4 onesu = {0x3F803F80u, 0x3F803F80u, 0x3F803F80u, 0x3F803F80u};
  const bf16x8 bones = __builtin_bit_cast(bf16x8, onesu);

  uint4 l00, l01, l02, l03, l10, l11, l12, l13, l20, l21, l22, l23;

  f32x4 liacc[2];
  f32x4 oacc[2][4];
#pragma unroll
  for (int mt = 0; mt < 2; ++mt) {
    liacc[mt] = (f32x4)0.0f;
#pragma unroll
    for (int nt = 0; nt < 4; ++nt) oacc[mt][nt] = (f32x4)0.0f;
  }

  async_cp16(kg0, Ks[0] + w * 512);
  async_cp16(kg1, Ks[0] + (w + 4) * 512);
  async_cp16(vg0, Vs[0] + w * 512);
  async_cp16(vg1, Vs[0] + (w + 4) * 512);
  lem_load(lemq, l00, l01, l02, l03);
  lemq += 8192;
  async_cp16(kg0 + (size_t)64 * HDIM, Ks[1] + w * 512);
  async_cp16(kg1 + (size_t)64 * HDIM, Ks[1] + (w + 4) * 512);
  async_cp16(vg0 + 64, Vs[1] + w * 512);
  async_cp16(vg1 + 64, Vs[1] + (w + 4) * 512);
  lem_load(lemq, l10, l11, l12, l13);
  lemq += 8192;

#define FLASH_COMPUTE(BUF, LSA, LSB, LSC, LSD)                                         \
  {                                                                                    \
    bf16x8 bk_[4][2], bv[4][2];                                                        \
    _Pragma("unroll") for (int nt = 0; nt < 4; ++nt)                                   \
      _Pragma("unroll") for (int ks = 0; ks < 2; ++ks)                                 \
        bk_[nt][ks] =                                                                  \
            ld_frag(&Ks[BUF][(nt * 16 + cc) * 64 + ((4 * ks + g + cc) & 7) * 8]);      \
    _Pragma("unroll") for (int nt = 0; nt < 4; ++nt)                                   \
      _Pragma("unroll") for (int ks = 0; ks < 2; ++ks)                                 \
        bv[nt][ks] =                                                                   \
            ld_frag(&Vs[BUF][(nt * 16 + cc) * 64 + ((4 * ks + g + cc) & 7) * 8]);      \
    bf16x8 ap[2][2];                                                                   \
    _Pragma("unroll") for (int mt = 0; mt < 2; ++mt) {                                 \
      f32x4 sacc[4];                                                                   \
      const uint4 ea = (mt == 0) ? LSA : LSC;                                          \
      const uint4 eb = (mt == 0) ? LSB : LSD;                                          \
      sacc[0][0] = bflo(ea.x); sacc[0][1] = bfhi(ea.x);                                \
      sacc[0][2] = bflo(ea.y); sacc[0][3] = bfhi(ea.y);                                \
      sacc[1][0] = bflo(ea.z); sacc[1][1] = bfhi(ea.z);                                \
      sacc[1][2] = bflo(ea.w); sacc[1][3] = bfhi(ea.w);                                \
      sacc[2][0] = bflo(eb.x); sacc[2][1] = bfhi(eb.x);                                \
      sacc[2][2] = bflo(eb.y); sacc[2][3] = bfhi(eb.y);                                \
      sacc[3][0] = bflo(eb.z); sacc[3][1] = bfhi(eb.z);                                \
      sacc[3][2] = bflo(eb.w); sacc[3][3] = bfhi(eb.w);                                \
      _Pragma("unroll") for (int nt = 0; nt < 4; ++nt)                                 \
        _Pragma("unroll") for (int ks = 0; ks < 2; ++ks)                               \
          sacc[nt] = __builtin_amdgcn_mfma_f32_16x16x32_bf16(bk_[nt][ks], aq[mt][ks],  \
                                                             sacc[nt], 0, 0, 0);       \
      float p[4][4];                                                                   \
      _Pragma("unroll") for (int nt = 0; nt < 4; ++nt)                                 \
        _Pragma("unroll") for (int r = 0; r < 4; ++r)                                  \
          p[nt][r] = __builtin_amdgcn_exp2f(sacc[nt][r]);                              \
      unsigned int wd[8];                                                              \
      _Pragma("unroll") for (int ks = 0; ks < 2; ++ks) {                               \
        wd[ks * 4 + 0] = pack2(p[2 * ks][1],     p[2 * ks][0]);                        \
        wd[ks * 4 + 1] = pack2(p[2 * ks][3],     p[2 * ks][2]);                        \
        wd[ks * 4 + 2] = pack2(p[2 * ks + 1][1], p[2 * ks + 1][0]);                    \
        wd[ks * 4 + 3] = pack2(p[2 * ks + 1][3], p[2 * ks + 1][2]);                    \
        u32x4 uv = {wd[ks * 4], wd[ks * 4 + 1], wd[ks * 4 + 2], wd[ks * 4 + 3]};       \
        ap[mt][ks] = __builtin_bit_cast(bf16x8, uv);                                   \
      }                                                                                \
    }                                                                                  \
    _Pragma("unroll") for (int mt = 0; mt < 2; ++mt) {                                 \
      _Pragma("unroll") for (int nt = 0; nt < 4; ++nt)                                 \
        _Pragma("unroll") for (int ks = 0; ks < 2; ++ks)                               \
          oacc[mt][nt] = __builtin_amdgcn_mfma_f32_16x16x32_bf16(ap[mt][ks], bv[nt][ks],\
                                                                 oacc[mt][nt], 0, 0, 0);\
      _Pragma("unroll") for (int ks = 0; ks < 2; ++ks)                                 \
        liacc[mt] = __builtin_amdgcn_mfma_f32_16x16x32_bf16(ap[mt][ks], bones,         \
                                                            liacc[mt], 0, 0, 0);       \
    }                                                                                  \
  }

#define FITER(KT, CBUF, SBUF, VMC, ISSUE, UA, UB, UC, UD, LA, LB, LC, LD)              \
  {                                                                                    \
    asm volatile("s_waitcnt vmcnt(" VMC ")" ::: "memory");                             \
    __builtin_amdgcn_sched_barrier(0);                                                 \
    asm volatile("s_barrier" ::: "memory");                                            \
    __builtin_amdgcn_sched_barrier(0);                                                 \
    if (ISSUE) {                                                                       \
      const size_t ko = (size_t)((KT) + 2) * 64;                                       \
      async_cp16(kg0 + ko * HDIM, Ks[SBUF] + w * 512);                                 \
      async_cp16(kg1 + ko * HDIM, Ks[SBUF] + (w + 4) * 512);                           \
      async_cp16(vg0 + ko, Vs[SBUF] + w * 512);                                        \
      async_cp16(vg1 + ko, Vs[SBUF] + (w + 4) * 512);                                  \
      lem_load(lemq, LA, LB, LC, LD);                                                  \
      lemq += 8192;                                                                    \
    }                                                                                  \
    FLASH_COMPUTE(CBUF, UA, UB, UC, UD);                                               \
  }

  for (int kt = 0; kt < 30; kt += 3) {
    FITER(kt + 0, 0, 2, "8", true,  l00, l01, l02, l03, l20, l21, l22, l23)
    FITER(kt + 1, 1, 0, "8", true,  l10, l11, l12, l13, l00, l01, l02, l03)
    FITER(kt + 2, 2, 1, "8", true,  l20, l21, l22, l23, l10, l11, l12, l13)
  }
  FITER(30, 0, 0, "8", false, l00, l01, l02, l03, l00, l01, l02, l03)
  FITER(31, 1, 0, "0", false, l10, l11, l12, l13, l10, l11, l12, l13)

#undef FITER
#undef FLASH_COMPUTE

#pragma unroll
  for (int mt = 0; mt < 2; ++mt) {
#pragma unroll
    for (int r = 0; r < 4; ++r) {
      float inv = 1.0f / liacc[mt][r];
      int qrow = q0 + w * 32 + mt * 16 + g * 4 + r;
#pragma unroll
      for (int nt = 0; nt < 4; ++nt)
        out[((size_t)b * LL + qrow) * 1024 + h * 64 + nt * 16 + cc] = oacc[mt][nt][r] * inv;
    }
  }
}

extern "C" void kernel_launch(void* const* d_in, const int* in_sizes, int n_in,
                              void* d_out, int out_size, void* d_ws, size_t ws_size,
                              hipStream_t stream) {
  const float* x    = (const float*)d_in[0];
  const float* mask = (const float*)d_in[1];
  const float* Wq   = (const float*)d_in[2];
  const float* bq   = (const float*)d_in[3];
  const float* Wk   = (const float*)d_in[4];
  const float* bk   = (const float*)d_in[5];
  const float* Wv   = (const float*)d_in[6];
  const float* bv   = (const float*)d_in[7];
  float* out = (float*)d_out;
  (void)in_sizes; (void)n_in; (void)out_size; (void)ws_size;

  char* ws = (char*)d_ws;
  // layout: qkv @0 (24 MiB); xb @24 (8 MiB); Wt @32 (6 MiB);
  // lem @24 (16 MiB) overlaps xb/Wt — dead after qkv_gemm (same-stream serialization)
  unsigned short* qkv = (unsigned short*)(ws);
  unsigned short* xb  = (unsigned short*)(ws + (24u << 20));
  unsigned short* Wt  = (unsigned short*)(ws + (32u << 20));
  unsigned short* lem = (unsigned short*)(ws + (24u << 20));

  prep_kernel<<<dim3(16, 16, 4), dim3(256), 0, stream>>>(x, Wq, Wk, Wv, xb, Wt);
  qkv_gemm_kernel<<<dim3(8, 32, 3), dim3(256), 0, stream>>>(xb, Wt, bq, bk, bv, qkv);
  lem_prep_kernel<<<dim3(16, 32, 2), dim3(256), 0, stream>>>(mask, lem);
  flash_kernel<<<dim3(16, 32), dim3(256), 0, stream>>>(qkv, qkv + 4194304, qkv + 8388608,
                                                       lem, out);
}